// Round 1
// 1926.533 us; speedup vs baseline: 1.6788x; 1.6788x over previous
//
#include <hip/hip_runtime.h>

// ---------------------------------------------------------------------------
// ShoppingLSTM: 12-layer LSTM (layer0 own weights, layers1..11 shared),
// B=128, S=256, H=EMB=256, OUT=10.
//
// R5: batch-row-local recurrence. Re-slice each layer's 16 blocks from
// (all 128 rows x 16 gate-cols) to (32 rows x 256 gate-cols):
//   block = (layer l, rowgroup rg of 32 rows, colslice s of 64 h-cols).
// The h(t-1) dependency now needs only the 4 sibling blocks (same l,rg)
// instead of a 16-block all-to-all; publish is a per-block monotone flag
// (no atomic-RMW aggregation). x-part (layer l-1 output, runs ahead) is
// loaded in the same window as the h-part. A-frags are staged once into
// LDS in MFMA-frag layout (each wave loads a kt-quarter; all waves
// broadcast-read), deduplicating the former 4x wave-redundant LLC loads.
// Per-thread weight footprint (64 half8 B-frags) and per-wave MFMA count
// (128/step) are identical to R4; only indexing + protocol topology change.
// ---------------------------------------------------------------------------

#define BB 128
#define SS 256
#define LL 12
#define NBLK 192
#define AGENT __HIP_MEMORY_SCOPE_AGENT

typedef _Float16 half8 __attribute__((ext_vector_type(8)));
typedef float f32x4 __attribute__((ext_vector_type(4)));

union U8 { unsigned long long u; _Float16 h[4]; };

__device__ __forceinline__ float sigf(float x) {
    return 1.0f / (1.0f + __expf(-x));
}
__device__ __forceinline__ float tanhf_fast(float x) {
    return 1.0f - 2.0f / (1.0f + __expf(2.0f * x));
}
__device__ __forceinline__ half8 cvt8(const float* p) {
    float4 u = *(const float4*)p;
    float4 v = *(const float4*)(p + 4);
    half8 h;
    h[0] = (_Float16)u.x; h[1] = (_Float16)u.y; h[2] = (_Float16)u.z; h[3] = (_Float16)u.w;
    h[4] = (_Float16)v.x; h[5] = (_Float16)v.y; h[6] = (_Float16)v.z; h[7] = (_Float16)v.w;
    return h;
}
__device__ __forceinline__ int pld(const int* p) {
    return __hip_atomic_load(p, __ATOMIC_RELAXED, AGENT);
}

// ---- batched device-coherent loads (self-contained: loads + terminal
// waitcnt in ONE asm block, outputs early-clobbered; R4 safety doctrine) ----
// One base, 16 frags at byte offsets k*64 (weight fragments, one-time).
__device__ __forceinline__ void ld16w(const _Float16* p, half8 (&r)[16]) {
    asm volatile(
        "global_load_dwordx4 %0, %16, off sc0 sc1\n\t"
        "global_load_dwordx4 %1, %16, off offset:64 sc0 sc1\n\t"
        "global_load_dwordx4 %2, %16, off offset:128 sc0 sc1\n\t"
        "global_load_dwordx4 %3, %16, off offset:192 sc0 sc1\n\t"
        "global_load_dwordx4 %4, %16, off offset:256 sc0 sc1\n\t"
        "global_load_dwordx4 %5, %16, off offset:320 sc0 sc1\n\t"
        "global_load_dwordx4 %6, %16, off offset:384 sc0 sc1\n\t"
        "global_load_dwordx4 %7, %16, off offset:448 sc0 sc1\n\t"
        "global_load_dwordx4 %8, %16, off offset:512 sc0 sc1\n\t"
        "global_load_dwordx4 %9, %16, off offset:576 sc0 sc1\n\t"
        "global_load_dwordx4 %10, %16, off offset:640 sc0 sc1\n\t"
        "global_load_dwordx4 %11, %16, off offset:704 sc0 sc1\n\t"
        "global_load_dwordx4 %12, %16, off offset:768 sc0 sc1\n\t"
        "global_load_dwordx4 %13, %16, off offset:832 sc0 sc1\n\t"
        "global_load_dwordx4 %14, %16, off offset:896 sc0 sc1\n\t"
        "global_load_dwordx4 %15, %16, off offset:960 sc0 sc1\n\t"
        "s_waitcnt vmcnt(0)"
        : "=&v"(r[0]), "=&v"(r[1]), "=&v"(r[2]), "=&v"(r[3]),
          "=&v"(r[4]), "=&v"(r[5]), "=&v"(r[6]), "=&v"(r[7]),
          "=&v"(r[8]), "=&v"(r[9]), "=&v"(r[10]), "=&v"(r[11]),
          "=&v"(r[12]), "=&v"(r[13]), "=&v"(r[14]), "=&v"(r[15])
        : "v"(p)
        : "memory");
}
// Two bases (M-tile 0 / M-tile 1), 2 frags each at byte offsets 0/64.
__device__ __forceinline__ void ld2x2(const _Float16* p0, const _Float16* p1,
                                      half8 (&r)[4]) {
    asm volatile(
        "global_load_dwordx4 %0, %4, off sc0 sc1\n\t"
        "global_load_dwordx4 %1, %4, off offset:64 sc0 sc1\n\t"
        "global_load_dwordx4 %2, %5, off sc0 sc1\n\t"
        "global_load_dwordx4 %3, %5, off offset:64 sc0 sc1\n\t"
        "s_waitcnt vmcnt(0)"
        : "=&v"(r[0]), "=&v"(r[1]), "=&v"(r[2]), "=&v"(r[3])
        : "v"(p0), "v"(p1)
        : "memory");
}
__device__ __forceinline__ void stcg(_Float16* p, half8 v) {
    asm volatile("global_store_dwordx4 %0, %1, off sc0 sc1" :: "v"(p), "v"(v) : "memory");
}
__device__ __forceinline__ void vdrain() {
    asm volatile("s_waitcnt vmcnt(0)" ::: "memory");
}

// bar layout (ints, memset 0 each launch):
//   bar[FLG(l,rg,s)]  monotone per-block progress flag (= completed steps)
//   bar[3072]         init-barrier counter
#define FLG(L,R,S) ((((L) * 16 + (R) * 4 + (S)) * 16))

__global__ __launch_bounds__(256, 1) void lstm_wavefront(
    const int* __restrict__ xind,     // [128][256]
    const float* __restrict__ emb,    // [50000][256]
    const float* __restrict__ W0, const float* __restrict__ U0,
    const float* __restrict__ b0,
    const float* __restrict__ Wsh, const float* __restrict__ Ush,
    const float* __restrict__ bsh,
    const float* __restrict__ fcW, const float* __restrict__ fcb,
    float* __restrict__ out,          // [128][10]
    _Float16* __restrict__ wt,        // ws: [2][1024][512] transposed fp16 weights
    _Float16* __restrict__ hbuf,      // ws: [12][ring][128][256] h ring
    float* __restrict__ h32,          // ws: [128][256] final h fp32
    int* __restrict__ bar,            // ws: counters (memset 0)
    int ring, int hmask)
{
    const int l    = blockIdx.x >> 4;
    const int sub  = blockIdx.x & 15;
    const int rg   = sub >> 2;         // rowgroup: rows rg*32 .. rg*32+31
    const int s    = sub & 3;          // colslice: h-cols s*64 .. s*64+63
    const int wave = threadIdx.x >> 6;
    const int lane = threadIdx.x & 63;
    const int quad = lane >> 4;
    const int ln   = lane & 15;

    __shared__ float tile[32][33];
    __shared__ half8 axs[2][8][64];        // staged x A-frags [mt][kt][lane]
    __shared__ half8 ahs[2][8][64];        // staged h A-frags [mt][kt][lane]
    __shared__ unsigned short hsm[32][64]; // h pack: [row][hcol-within-slice]

    // ---- phase 0: transpose W/U fp32 [256][1024] -> wt fp16 [set][n][k] ----
    {
        const int rr = threadIdx.x >> 5;
        const int cc = threadIdx.x & 31;
        const int nl = threadIdx.x >> 3;
        const int kg = threadIdx.x & 7;
        for (int tidx = blockIdx.x; tidx < 1024; tidx += NBLK) {
            const int job   = tidx >> 8;        // 0:W0 1:U0 2:Ws 3:Us
            const int tk    = (tidx >> 5) & 7;
            const int tn    = tidx & 31;
            const float* src = (job == 0) ? W0 : (job == 1) ? U0 : (job == 2) ? Wsh : Ush;
            const int set   = job >> 1;
            const int khalf = job & 1;
            __syncthreads();
            #pragma unroll
            for (int r = 0; r < 4; ++r)
                tile[rr + r * 8][cc] = src[(size_t)(tk * 32 + rr + r * 8) * 1024 + tn * 32 + cc];
            __syncthreads();
            U8 pk;
            #pragma unroll
            for (int j = 0; j < 4; ++j)
                pk.h[j] = (_Float16)tile[kg * 4 + j][nl];
            __hip_atomic_store(
                (unsigned long long*)(wt + ((size_t)(set * 1024 + tn * 32 + nl)) * 512
                                      + khalf * 256 + tk * 32 + kg * 4),
                pk.u, __ATOMIC_RELAXED, AGENT);
        }
    }
    // ---- init barrier (once) ----
    vdrain();
    __syncthreads();
    if (threadIdx.x == 0) {
        __hip_atomic_fetch_add(&bar[3072], 1, __ATOMIC_RELAXED, AGENT);
        while (pld(&bar[3072]) < NBLK) __builtin_amdgcn_s_sleep(2);
    }
    __syncthreads();

    // ---- weight fragments -> registers (stay for all 256 steps) ----
    // B-frag for mfma_f32_16x16x32_f16: n = q*256 + s*64 + wave*16 + ln,
    // k = kt*32 + quad*8 + j; kt 0..7 = W rows, kt 8..15 = U rows.
    half8 bf[4][16];
    {
        const int set = (l == 0) ? 0 : 1;
        #pragma unroll
        for (int q = 0; q < 4; ++q)
            ld16w(wt + ((size_t)(set * 1024 + q * 256 + s * 64 + wave * 16 + ln)) * 512
                     + quad * 8,
                  bf[q]);
    }
    float bias_q[4];
    {
        const float* bv = (l == 0) ? b0 : bsh;
        #pragma unroll
        for (int q = 0; q < 4; ++q)
            bias_q[q] = bv[q * 256 + s * 64 + wave * 16 + ln];
    }

    float creg[2][4];
    const int r2  = threadIdx.x >> 3;   // pack: row within 32
    const int c2  = threadIdx.x & 7;    // pack: 16B chunk within 64 cols
    const int ktx = wave * 2;           // this thread stages kt = ktx, ktx+1

    for (int t = 0; t < SS; ++t) {
        // ---- waits spread over 3 waves (latency = max, not sum) ----
        if (wave == 3 && lane < 4) {
            // x ready: layer l-1 rowgroup rg, all 4 col-slices finished step t
            if (l > 0)
                while (pld(&bar[FLG(l - 1, rg, lane)]) < t + 1) __builtin_amdgcn_s_sleep(1);
        } else if (wave == 1 && lane < 4) {
            // h(t-1) ready: own layer, own rowgroup, all 4 col-slices
            if (t > 0)
                while (pld(&bar[FLG(l, rg, lane)]) < t) __builtin_amdgcn_s_sleep(1);
        } else if (wave == 2 && lane < 4) {
            // backpressure: layer l+1 consumed ring slot we are about to overwrite
            if (l < LL - 1 && t >= ring)
                while (pld(&bar[FLG(l + 1, rg, lane)]) < t - ring + 1) __builtin_amdgcn_s_sleep(1);
        }
        __syncthreads();

        // ---- cooperative staging: each thread loads its kt-quarter ----
        if (l == 0) {
            #pragma unroll
            for (int mt = 0; mt < 2; ++mt) {
                const int row = rg * 32 + mt * 16 + ln;
                const int idx = xind[row * SS + t];
                const float* e = emb + (size_t)idx * 256 + quad * 8;
                axs[mt][ktx][lane]     = cvt8(e + ktx * 32);
                axs[mt][ktx + 1][lane] = cvt8(e + (ktx + 1) * 32);
            }
        } else {
            const _Float16* xb = hbuf + (((size_t)((l - 1) * ring + (t & hmask))) << 15);
            half8 r[4];
            ld2x2(xb + (rg * 32 + ln) * 256 + ktx * 32 + quad * 8,
                  xb + (rg * 32 + 16 + ln) * 256 + ktx * 32 + quad * 8, r);
            axs[0][ktx][lane] = r[0]; axs[0][ktx + 1][lane] = r[1];
            axs[1][ktx][lane] = r[2]; axs[1][ktx + 1][lane] = r[3];
        }
        if (t > 0) {
            const _Float16* hb = hbuf + (((size_t)(l * ring + ((t - 1) & hmask))) << 15);
            half8 r[4];
            ld2x2(hb + (rg * 32 + ln) * 256 + ktx * 32 + quad * 8,
                  hb + (rg * 32 + 16 + ln) * 256 + ktx * 32 + quad * 8, r);
            ahs[0][ktx][lane] = r[0]; ahs[0][ktx + 1][lane] = r[1];
            ahs[1][ktx][lane] = r[2]; ahs[1][ktx + 1][lane] = r[3];
        }
        __syncthreads();

        // ---- MFMA: acc = x@W (+ h@U) for this block's 2 Mtiles x 4 quads ----
        f32x4 acc[2][4];
        #pragma unroll
        for (int mt = 0; mt < 2; ++mt)
            #pragma unroll
            for (int q = 0; q < 4; ++q)
                acc[mt][q] = (f32x4){0.f, 0.f, 0.f, 0.f};

        #pragma unroll
        for (int kt = 0; kt < 8; ++kt) {
            half8 a0 = axs[0][kt][lane];
            half8 a1 = axs[1][kt][lane];
            #pragma unroll
            for (int q = 0; q < 4; ++q) {
                acc[0][q] = __builtin_amdgcn_mfma_f32_16x16x32_f16(a0, bf[q][kt], acc[0][q], 0, 0, 0);
                acc[1][q] = __builtin_amdgcn_mfma_f32_16x16x32_f16(a1, bf[q][kt], acc[1][q], 0, 0, 0);
            }
        }
        if (t > 0) {
            #pragma unroll
            for (int kt = 0; kt < 8; ++kt) {
                half8 a0 = ahs[0][kt][lane];
                half8 a1 = ahs[1][kt][lane];
                #pragma unroll
                for (int q = 0; q < 4; ++q) {
                    acc[0][q] = __builtin_amdgcn_mfma_f32_16x16x32_f16(a0, bf[q][kt + 8], acc[0][q], 0, 0, 0);
                    acc[1][q] = __builtin_amdgcn_mfma_f32_16x16x32_f16(a1, bf[q][kt + 8], acc[1][q], 0, 0, 0);
                }
            }
        }

        // ---- LSTM cell (D layout: col = ln, row = quad*4 + r within Mtile) ----
        #pragma unroll
        for (int mt = 0; mt < 2; ++mt) {
            #pragma unroll
            for (int r = 0; r < 4; ++r) {
                float gi = acc[mt][0][r] + bias_q[0];
                float gf = acc[mt][1][r] + bias_q[1];
                float gg = acc[mt][2][r] + bias_q[2];
                float go = acc[mt][3][r] + bias_q[3];
                float cold = (t == 0) ? 0.0f : creg[mt][r];
                float cnew = sigf(gf) * cold + sigf(gi) * tanhf_fast(gg);
                creg[mt][r] = cnew;
                float h = sigf(go) * tanhf_fast(cnew);
                int prow = mt * 16 + quad * 4 + r;          // row within 32
                _Float16 hh = (_Float16)h;
                hsm[prow][wave * 16 + ln] = *(unsigned short*)&hh;
                if (l == LL - 1 && t == SS - 1)
                    __hip_atomic_store(
                        &h32[(rg * 32 + prow) * 256 + s * 64 + wave * 16 + ln],
                        h, __ATOMIC_RELAXED, AGENT);
            }
        }
        __syncthreads();
        // repack LDS -> one coherent 16B store per thread (4KB slice)
        {
            _Float16* hd = hbuf + (((size_t)(l * ring + (t & hmask))) << 15)
                         + (rg * 32 + r2) * 256 + s * 64 + c2 * 8;
            stcg(hd, *(const half8*)&hsm[r2][c2 * 8]);
        }
        vdrain();
        __syncthreads();
        // ---- publish progress: single monotone flag, no atomic-RMW ----
        if (threadIdx.x == 0)
            __hip_atomic_store(&bar[FLG(l, rg, s)], t + 1, __ATOMIC_RELAXED, AGENT);
    }

    // ---- final FC: block (11, rg, 0) -> batch rows rg*32 .. rg*32+31 ----
    if (l == LL - 1 && s == 0) {
        if (threadIdx.x < 4)
            while (pld(&bar[FLG(LL - 1, rg, threadIdx.x)]) < SS) __builtin_amdgcn_s_sleep(1);
        __syncthreads();
        for (int idx = threadIdx.x; idx < 320; idx += 256) {
            int b = rg * 32 + idx / 10, o = idx % 10;
            float a0 = 0.f, a1 = 0.f, a2 = 0.f, a3 = 0.f;
            for (int d = 0; d < 256; d += 4) {
                a0 += __hip_atomic_load(&h32[b * 256 + d + 0], __ATOMIC_RELAXED, AGENT) * fcW[(d + 0) * 10 + o];
                a1 += __hip_atomic_load(&h32[b * 256 + d + 1], __ATOMIC_RELAXED, AGENT) * fcW[(d + 1) * 10 + o];
                a2 += __hip_atomic_load(&h32[b * 256 + d + 2], __ATOMIC_RELAXED, AGENT) * fcW[(d + 2) * 10 + o];
                a3 += __hip_atomic_load(&h32[b * 256 + d + 3], __ATOMIC_RELAXED, AGENT) * fcW[(d + 3) * 10 + o];
            }
            out[b * 10 + o] = fcb[o] + ((a0 + a1) + (a2 + a3));
        }
    }
}

extern "C" void kernel_launch(void* const* d_in, const int* in_sizes, int n_in,
                              void* d_out, int out_size, void* d_ws, size_t ws_size,
                              hipStream_t stream) {
    const int*   xind = (const int*)d_in[0];
    const float* emb  = (const float*)d_in[1];
    const float* W0   = (const float*)d_in[2];
    const float* U0   = (const float*)d_in[3];
    const float* b0   = (const float*)d_in[4];
    const float* Wsh  = (const float*)d_in[5];
    const float* Ush  = (const float*)d_in[6];
    const float* bsh  = (const float*)d_in[7];
    const float* fcW  = (const float*)d_in[8];
    const float* fcb  = (const float*)d_in[9];
    float* out = (float*)d_out;

    const size_t wtB = (size_t)2 * 1024 * 512 * 2;  // 2 MB
    auto need = [&](int r) {
        return wtB + (size_t)LL * r * 128 * 256 * 2 + 131072 + 16384;
    };
    int ring = (ws_size >= need(8)) ? 8 : (ws_size >= need(4)) ? 4 : 2;

    char* ws = (char*)d_ws;
    _Float16* wt   = (_Float16*)ws;
    _Float16* hbuf = (_Float16*)(ws + wtB);
    float*    h32  = (float*)(ws + wtB + (size_t)LL * ring * 128 * 256 * 2);
    int*      bar  = (int*)((char*)h32 + 131072);

    hipMemsetAsync(bar, 0, 16384, stream);
    hipLaunchKernelGGL(lstm_wavefront, dim3(NBLK), dim3(256), 0, stream,
                       xind, emb, W0, U0, b0, Wsh, Ush, bsh, fcW, fcb, out,
                       wt, hbuf, h32, bar, ring, ring - 1);
}

// Round 6
// 1872.140 us; speedup vs baseline: 1.7276x; 1.0291x over previous
//
#include <hip/hip_runtime.h>

// ---------------------------------------------------------------------------
// ShoppingLSTM: 12-layer LSTM (layer0 own weights, layers1..11 shared),
// B=128, S=256, H=EMB=256, OUT=10.
//
// R10: safe-harvest round. Protocol is BIT-IDENTICAL to R5 (measured 1926us:
// (l, rowgroup, colslice) topology, eager per-block monotone FLG flags,
// agent-scope polls, ring-buffered hbuf, identical wait structure). Two
// surgical protocol-free edits on top:
//   EDIT 1: merged x+h staging batch — R5 issued two serialized
//           vmcnt(0) load batches (x then h) = 2 LLC round trips on the
//           serial t-edge; ld8_glob does all 8 loads under ONE terminal
//           vmcnt(0), removing one RT per step.
//   EDIT 2: wave s (own colslice) reads its h A-frags from LDS (hsm holds
//           exactly this block's step-(t-1) h slice) instead of re-loading
//           them through the LLC: -25% h exchange traffic, block-local.
// The R6/R7 L2-colocation experiment is parked: two opaque ExceptionGroup
// rounds with zero counters; this round re-establishes a measured baseline.
// ---------------------------------------------------------------------------

#define BB 128
#define SS 256
#define LL 12
#define NBLK 192
#define AGENT __HIP_MEMORY_SCOPE_AGENT

typedef _Float16 half8 __attribute__((ext_vector_type(8)));
typedef float f32x4 __attribute__((ext_vector_type(4)));

union U8 { unsigned long long u; _Float16 h[4]; };

__device__ __forceinline__ float sigf(float x) {
    return 1.0f / (1.0f + __expf(-x));
}
__device__ __forceinline__ float tanhf_fast(float x) {
    return 1.0f - 2.0f / (1.0f + __expf(2.0f * x));
}
__device__ __forceinline__ half8 cvt8(const float* p) {
    float4 u = *(const float4*)p;
    float4 v = *(const float4*)(p + 4);
    half8 h;
    h[0] = (_Float16)u.x; h[1] = (_Float16)u.y; h[2] = (_Float16)u.z; h[3] = (_Float16)u.w;
    h[4] = (_Float16)v.x; h[5] = (_Float16)v.y; h[6] = (_Float16)v.z; h[7] = (_Float16)v.w;
    return h;
}
__device__ __forceinline__ int pld(const int* p) {
    return __hip_atomic_load(p, __ATOMIC_RELAXED, AGENT);
}

// ---- batched device-coherent loads (self-contained: loads + terminal
// waitcnt in ONE asm block, outputs early-clobbered; R4 safety doctrine) ----
// One base, 16 frags at byte offsets k*64 (weight fragments, one-time).
__device__ __forceinline__ void ld16w(const _Float16* p, half8 (&r)[16]) {
    asm volatile(
        "global_load_dwordx4 %0, %16, off sc0 sc1\n\t"
        "global_load_dwordx4 %1, %16, off offset:64 sc0 sc1\n\t"
        "global_load_dwordx4 %2, %16, off offset:128 sc0 sc1\n\t"
        "global_load_dwordx4 %3, %16, off offset:192 sc0 sc1\n\t"
        "global_load_dwordx4 %4, %16, off offset:256 sc0 sc1\n\t"
        "global_load_dwordx4 %5, %16, off offset:320 sc0 sc1\n\t"
        "global_load_dwordx4 %6, %16, off offset:384 sc0 sc1\n\t"
        "global_load_dwordx4 %7, %16, off offset:448 sc0 sc1\n\t"
        "global_load_dwordx4 %8, %16, off offset:512 sc0 sc1\n\t"
        "global_load_dwordx4 %9, %16, off offset:576 sc0 sc1\n\t"
        "global_load_dwordx4 %10, %16, off offset:640 sc0 sc1\n\t"
        "global_load_dwordx4 %11, %16, off offset:704 sc0 sc1\n\t"
        "global_load_dwordx4 %12, %16, off offset:768 sc0 sc1\n\t"
        "global_load_dwordx4 %13, %16, off offset:832 sc0 sc1\n\t"
        "global_load_dwordx4 %14, %16, off offset:896 sc0 sc1\n\t"
        "global_load_dwordx4 %15, %16, off offset:960 sc0 sc1\n\t"
        "s_waitcnt vmcnt(0)"
        : "=&v"(r[0]), "=&v"(r[1]), "=&v"(r[2]), "=&v"(r[3]),
          "=&v"(r[4]), "=&v"(r[5]), "=&v"(r[6]), "=&v"(r[7]),
          "=&v"(r[8]), "=&v"(r[9]), "=&v"(r[10]), "=&v"(r[11]),
          "=&v"(r[12]), "=&v"(r[13]), "=&v"(r[14]), "=&v"(r[15])
        : "v"(p)
        : "memory");
}
// 4 coherent loads, two bases (mt0/mt1), offsets 0/64 each.
__device__ __forceinline__ void ld4_2b(const _Float16* p0, const _Float16* p1,
                                       half8 (&r)[4]) {
    asm volatile(
        "global_load_dwordx4 %0, %4, off sc0 sc1\n\t"
        "global_load_dwordx4 %1, %4, off offset:64 sc0 sc1\n\t"
        "global_load_dwordx4 %2, %5, off sc0 sc1\n\t"
        "global_load_dwordx4 %3, %5, off offset:64 sc0 sc1\n\t"
        "s_waitcnt vmcnt(0)"
        : "=&v"(r[0]), "=&v"(r[1]), "=&v"(r[2]), "=&v"(r[3])
        : "v"(p0), "v"(p1)
        : "memory");
}
// EDIT 1: merged x + h staging, 4 bases, ONE terminal wait (saves one
// serialized LLC round trip per step vs two ld4_2b batches).
__device__ __forceinline__ void ld8_glob(const _Float16* px0, const _Float16* px1,
                                         const _Float16* ph0, const _Float16* ph1,
                                         half8 (&rx)[4], half8 (&rh)[4]) {
    asm volatile(
        "global_load_dwordx4 %0, %8, off sc0 sc1\n\t"
        "global_load_dwordx4 %1, %8, off offset:64 sc0 sc1\n\t"
        "global_load_dwordx4 %2, %9, off sc0 sc1\n\t"
        "global_load_dwordx4 %3, %9, off offset:64 sc0 sc1\n\t"
        "global_load_dwordx4 %4, %10, off sc0 sc1\n\t"
        "global_load_dwordx4 %5, %10, off offset:64 sc0 sc1\n\t"
        "global_load_dwordx4 %6, %11, off sc0 sc1\n\t"
        "global_load_dwordx4 %7, %11, off offset:64 sc0 sc1\n\t"
        "s_waitcnt vmcnt(0)"
        : "=&v"(rx[0]), "=&v"(rx[1]), "=&v"(rx[2]), "=&v"(rx[3]),
          "=&v"(rh[0]), "=&v"(rh[1]), "=&v"(rh[2]), "=&v"(rh[3])
        : "v"(px0), "v"(px1), "v"(ph0), "v"(ph1)
        : "memory");
}
__device__ __forceinline__ void stcg(_Float16* p, half8 v) {
    asm volatile("global_store_dwordx4 %0, %1, off sc0 sc1" :: "v"(p), "v"(v) : "memory");
}
__device__ __forceinline__ void vdrain() {
    asm volatile("s_waitcnt vmcnt(0)" ::: "memory");
}

// bar layout (ints, memset 0 each launch):
//   bar[FLG(l,rg,s)]  monotone per-block progress flag (= completed steps)
//   bar[3072]         init-barrier counter
#define FLG(L,R,S) ((((L) * 16 + (R) * 4 + (S)) * 16))

__global__ __launch_bounds__(256, 1) void lstm_wavefront(
    const int* __restrict__ xind,     // [128][256]
    const float* __restrict__ emb,    // [50000][256]
    const float* __restrict__ W0, const float* __restrict__ U0,
    const float* __restrict__ b0,
    const float* __restrict__ Wsh, const float* __restrict__ Ush,
    const float* __restrict__ bsh,
    const float* __restrict__ fcW, const float* __restrict__ fcb,
    float* __restrict__ out,          // [128][10]
    _Float16* __restrict__ wt,        // ws: [2][1024][512] transposed fp16 weights
    _Float16* __restrict__ hbuf,      // ws: [12][ring][128][256] h ring
    float* __restrict__ h32,          // ws: [128][256] final h fp32
    int* __restrict__ bar,            // ws: counters (memset 0)
    int ring, int hmask)
{
    const int l    = blockIdx.x >> 4;
    const int sub  = blockIdx.x & 15;
    const int rg   = sub >> 2;         // rowgroup: rows rg*32 .. rg*32+31
    const int s    = sub & 3;          // colslice: h-cols s*64 .. s*64+63
    const int wave = threadIdx.x >> 6;
    const int lane = threadIdx.x & 63;
    const int quad = lane >> 4;
    const int ln   = lane & 15;

    __shared__ float tile[32][33];
    __shared__ half8 axs[2][8][64];        // staged x A-frags [mt][kt][lane]
    __shared__ half8 ahs[2][8][64];        // staged h A-frags [mt][kt][lane]
    __shared__ __align__(16) unsigned short hsm[32][64]; // h pack [row][col]

    // ---- phase 0: transpose W/U fp32 [256][1024] -> wt fp16 [set][n][k] ----
    {
        const int rr = threadIdx.x >> 5;
        const int cc = threadIdx.x & 31;
        const int nl = threadIdx.x >> 3;
        const int kg = threadIdx.x & 7;
        for (int tidx = blockIdx.x; tidx < 1024; tidx += NBLK) {
            const int job   = tidx >> 8;        // 0:W0 1:U0 2:Ws 3:Us
            const int tk    = (tidx >> 5) & 7;
            const int tn    = tidx & 31;
            const float* src = (job == 0) ? W0 : (job == 1) ? U0 : (job == 2) ? Wsh : Ush;
            const int set   = job >> 1;
            const int khalf = job & 1;
            __syncthreads();
            #pragma unroll
            for (int r = 0; r < 4; ++r)
                tile[rr + r * 8][cc] = src[(size_t)(tk * 32 + rr + r * 8) * 1024 + tn * 32 + cc];
            __syncthreads();
            U8 pk;
            #pragma unroll
            for (int j = 0; j < 4; ++j)
                pk.h[j] = (_Float16)tile[kg * 4 + j][nl];
            __hip_atomic_store(
                (unsigned long long*)(wt + ((size_t)(set * 1024 + tn * 32 + nl)) * 512
                                      + khalf * 256 + tk * 32 + kg * 4),
                pk.u, __ATOMIC_RELAXED, AGENT);
        }
    }
    // ---- init barrier (once) ----
    vdrain();
    __syncthreads();
    if (threadIdx.x == 0) {
        __hip_atomic_fetch_add(&bar[3072], 1, __ATOMIC_RELAXED, AGENT);
        while (pld(&bar[3072]) < NBLK) __builtin_amdgcn_s_sleep(2);
    }
    __syncthreads();

    // ---- weight fragments -> registers (stay for all 256 steps) ----
    // B-frag: n = q*256 + s*64 + wave*16 + ln; k = kt*32 + quad*8 + j
    // kt 0..7 = W rows (x), kt 8..15 = U rows (h).
    half8 bf[4][16];
    {
        const int set = (l == 0) ? 0 : 1;
        #pragma unroll
        for (int q = 0; q < 4; ++q)
            ld16w(wt + ((size_t)(set * 1024 + q * 256 + s * 64 + wave * 16 + ln)) * 512
                     + quad * 8,
                  bf[q]);
    }
    float bias_q[4];
    {
        const float* bv = (l == 0) ? b0 : bsh;
        #pragma unroll
        for (int q = 0; q < 4; ++q)
            bias_q[q] = bv[q * 256 + s * 64 + wave * 16 + ln];
    }

    float creg[2][4];
    const int r2  = threadIdx.x >> 3;   // pack: row within 32
    const int c2  = threadIdx.x & 7;    // pack: 16B chunk within 64 cols
    const int ktx = wave * 2;           // this thread stages kt = ktx, ktx+1
    const int col = s * 64 + wave * 16 + ln;

    for (int t = 0; t < SS; ++t) {
        // ---- waits spread over 3 waves (latency = max, not sum) ----
        if (wave == 3 && lane < 4) {
            // x ready: layer l-1 rowgroup rg, all 4 col-slices finished step t
            if (l > 0)
                while (pld(&bar[FLG(l - 1, rg, lane)]) < t + 1) __builtin_amdgcn_s_sleep(1);
        } else if (wave == 1 && lane < 4) {
            // h(t-1) ready: own layer, own rowgroup, all 4 col-slices
            if (t > 0)
                while (pld(&bar[FLG(l, rg, lane)]) < t) __builtin_amdgcn_s_sleep(1);
        } else if (wave == 2 && lane < 4) {
            // backpressure: layer l+1 consumed ring slot we are about to overwrite
            if (l < LL - 1 && t >= ring)
                while (pld(&bar[FLG(l + 1, rg, lane)]) < t - ring + 1) __builtin_amdgcn_s_sleep(1);
        }
        __syncthreads();

        // ---- cooperative staging: each thread loads its kt pair ----
        if (l == 0) {
            #pragma unroll
            for (int mt = 0; mt < 2; ++mt) {
                const int row = rg * 32 + mt * 16 + ln;
                const int idx = xind[row * SS + t];
                const float* e = emb + (size_t)idx * 256 + quad * 8;
                axs[mt][ktx][lane]     = cvt8(e + ktx * 32);
                axs[mt][ktx + 1][lane] = cvt8(e + (ktx + 1) * 32);
            }
            if (t > 0) {
                if (wave == s) {
                    // EDIT 2: own-slice h straight from LDS (step t-1 hsm)
                    ahs[0][ktx][lane]     = *(const half8*)&hsm[ln][quad * 8];
                    ahs[0][ktx + 1][lane] = *(const half8*)&hsm[ln][32 + quad * 8];
                    ahs[1][ktx][lane]     = *(const half8*)&hsm[16 + ln][quad * 8];
                    ahs[1][ktx + 1][lane] = *(const half8*)&hsm[16 + ln][32 + quad * 8];
                } else {
                    const _Float16* hb = hbuf + (((size_t)(l * ring + ((t - 1) & hmask))) << 15);
                    const _Float16* ph0 = hb + (rg * 32 + ln) * 256 + ktx * 32 + quad * 8;
                    half8 rh[4];
                    ld4_2b(ph0, ph0 + 16 * 256, rh);
                    ahs[0][ktx][lane] = rh[0]; ahs[0][ktx + 1][lane] = rh[1];
                    ahs[1][ktx][lane] = rh[2]; ahs[1][ktx + 1][lane] = rh[3];
                }
            }
        } else {
            const _Float16* xb = hbuf + (((size_t)((l - 1) * ring + (t & hmask))) << 15);
            const _Float16* px0 = xb + (rg * 32 + ln) * 256 + ktx * 32 + quad * 8;
            const _Float16* px1 = px0 + 16 * 256;
            if (t == 0) {
                half8 rx[4];
                ld4_2b(px0, px1, rx);
                axs[0][ktx][lane] = rx[0]; axs[0][ktx + 1][lane] = rx[1];
                axs[1][ktx][lane] = rx[2]; axs[1][ktx + 1][lane] = rx[3];
            } else if (wave == s) {
                half8 rx[4];
                ld4_2b(px0, px1, rx);
                axs[0][ktx][lane] = rx[0]; axs[0][ktx + 1][lane] = rx[1];
                axs[1][ktx][lane] = rx[2]; axs[1][ktx + 1][lane] = rx[3];
                // EDIT 2: own-slice h straight from LDS (step t-1 hsm)
                ahs[0][ktx][lane]     = *(const half8*)&hsm[ln][quad * 8];
                ahs[0][ktx + 1][lane] = *(const half8*)&hsm[ln][32 + quad * 8];
                ahs[1][ktx][lane]     = *(const half8*)&hsm[16 + ln][quad * 8];
                ahs[1][ktx + 1][lane] = *(const half8*)&hsm[16 + ln][32 + quad * 8];
            } else {
                // EDIT 1: x + h merged under a single vmcnt(0)
                const _Float16* hb = hbuf + (((size_t)(l * ring + ((t - 1) & hmask))) << 15);
                const _Float16* ph0 = hb + (rg * 32 + ln) * 256 + ktx * 32 + quad * 8;
                half8 rx[4], rh[4];
                ld8_glob(px0, px1, ph0, ph0 + 16 * 256, rx, rh);
                axs[0][ktx][lane] = rx[0]; axs[0][ktx + 1][lane] = rx[1];
                axs[1][ktx][lane] = rx[2]; axs[1][ktx + 1][lane] = rx[3];
                ahs[0][ktx][lane] = rh[0]; ahs[0][ktx + 1][lane] = rh[1];
                ahs[1][ktx][lane] = rh[2]; ahs[1][ktx + 1][lane] = rh[3];
            }
        }
        __syncthreads();

        // ---- MFMA: acc = x@W (+ h@U) for this block's 2 Mtiles x 4 quads ----
        f32x4 acc[2][4];
        #pragma unroll
        for (int mt = 0; mt < 2; ++mt)
            #pragma unroll
            for (int q = 0; q < 4; ++q)
                acc[mt][q] = (f32x4){0.f, 0.f, 0.f, 0.f};

        #pragma unroll
        for (int kt = 0; kt < 8; ++kt) {
            half8 a0 = axs[0][kt][lane];
            half8 a1 = axs[1][kt][lane];
            #pragma unroll
            for (int q = 0; q < 4; ++q) {
                acc[0][q] = __builtin_amdgcn_mfma_f32_16x16x32_f16(a0, bf[q][kt], acc[0][q], 0, 0, 0);
                acc[1][q] = __builtin_amdgcn_mfma_f32_16x16x32_f16(a1, bf[q][kt], acc[1][q], 0, 0, 0);
            }
        }
        if (t > 0) {
            #pragma unroll
            for (int kt = 0; kt < 8; ++kt) {
                half8 a0 = ahs[0][kt][lane];
                half8 a1 = ahs[1][kt][lane];
                #pragma unroll
                for (int q = 0; q < 4; ++q) {
                    acc[0][q] = __builtin_amdgcn_mfma_f32_16x16x32_f16(a0, bf[q][kt + 8], acc[0][q], 0, 0, 0);
                    acc[1][q] = __builtin_amdgcn_mfma_f32_16x16x32_f16(a1, bf[q][kt + 8], acc[1][q], 0, 0, 0);
                }
            }
        }

        // ---- LSTM cell (D layout: col = ln, row = quad*4 + r within Mtile) ----
        #pragma unroll
        for (int mt = 0; mt < 2; ++mt) {
            #pragma unroll
            for (int r = 0; r < 4; ++r) {
                float gi = acc[mt][0][r] + bias_q[0];
                float gf = acc[mt][1][r] + bias_q[1];
                float gg = acc[mt][2][r] + bias_q[2];
                float go = acc[mt][3][r] + bias_q[3];
                float cold = (t == 0) ? 0.0f : creg[mt][r];
                float cnew = sigf(gf) * cold + sigf(gi) * tanhf_fast(gg);
                creg[mt][r] = cnew;
                float h = sigf(go) * tanhf_fast(cnew);
                int prow = mt * 16 + quad * 4 + r;          // row within 32
                _Float16 hh = (_Float16)h;
                hsm[prow][wave * 16 + ln] = *(unsigned short*)&hh;
                if (l == LL - 1 && t == SS - 1)
                    __hip_atomic_store(&h32[(rg * 32 + prow) * 256 + col],
                                       h, __ATOMIC_RELAXED, AGENT);
            }
        }
        __syncthreads();
        // repack LDS -> one coherent 16B store per thread (4KB slice)
        {
            _Float16* hd = hbuf + (((size_t)(l * ring + (t & hmask))) << 15)
                         + (rg * 32 + r2) * 256 + s * 64 + c2 * 8;
            stcg(hd, *(const half8*)&hsm[r2][c2 * 8]);
        }
        vdrain();
        __syncthreads();
        // ---- publish progress: single monotone flag, no atomic-RMW ----
        if (threadIdx.x == 0)
            __hip_atomic_store(&bar[FLG(l, rg, s)], t + 1, __ATOMIC_RELAXED, AGENT);
    }

    // ---- final FC: block (11, rg, 0) -> batch rows rg*32 .. rg*32+31 ----
    if (l == LL - 1 && s == 0) {
        if (threadIdx.x < 4)
            while (pld(&bar[FLG(LL - 1, rg, threadIdx.x)]) < SS) __builtin_amdgcn_s_sleep(1);
        __syncthreads();
        for (int idx = threadIdx.x; idx < 320; idx += 256) {
            int b = rg * 32 + idx / 10, o = idx % 10;
            float a0 = 0.f, a1 = 0.f, a2 = 0.f, a3 = 0.f;
            for (int d = 0; d < 256; d += 4) {
                a0 += __hip_atomic_load(&h32[b * 256 + d + 0], __ATOMIC_RELAXED, AGENT) * fcW[(d + 0) * 10 + o];
                a1 += __hip_atomic_load(&h32[b * 256 + d + 1], __ATOMIC_RELAXED, AGENT) * fcW[(d + 1) * 10 + o];
                a2 += __hip_atomic_load(&h32[b * 256 + d + 2], __ATOMIC_RELAXED, AGENT) * fcW[(d + 2) * 10 + o];
                a3 += __hip_atomic_load(&h32[b * 256 + d + 3], __ATOMIC_RELAXED, AGENT) * fcW[(d + 3) * 10 + o];
            }
            out[b * 10 + o] = fcb[o] + ((a0 + a1) + (a2 + a3));
        }
    }
}

extern "C" void kernel_launch(void* const* d_in, const int* in_sizes, int n_in,
                              void* d_out, int out_size, void* d_ws, size_t ws_size,
                              hipStream_t stream) {
    const int*   xind = (const int*)d_in[0];
    const float* emb  = (const float*)d_in[1];
    const float* W0   = (const float*)d_in[2];
    const float* U0   = (const float*)d_in[3];
    const float* b0   = (const float*)d_in[4];
    const float* Wsh  = (const float*)d_in[5];
    const float* Ush  = (const float*)d_in[6];
    const float* bsh  = (const float*)d_in[7];
    const float* fcW  = (const float*)d_in[8];
    const float* fcb  = (const float*)d_in[9];
    float* out = (float*)d_out;

    const size_t wtB = (size_t)2 * 1024 * 512 * 2;  // 2 MB
    auto need = [&](int r) {
        return wtB + (size_t)LL * r * 128 * 256 * 2 + 131072 + 16384;
    };
    int ring = (ws_size >= need(8)) ? 8 : (ws_size >= need(4)) ? 4 : 2;

    char* ws = (char*)d_ws;
    _Float16* wt   = (_Float16*)ws;
    _Float16* hbuf = (_Float16*)(ws + wtB);
    float*    h32  = (float*)(ws + wtB + (size_t)LL * ring * 128 * 256 * 2);
    int*      bar  = (int*)((char*)h32 + 131072);

    hipMemsetAsync(bar, 0, 16384, stream);
    hipLaunchKernelGGL(lstm_wavefront, dim3(NBLK), dim3(256), 0, stream,
                       xind, emb, W0, U0, b0, Wsh, Ush, bsh, fcW, fcb, out,
                       wt, hbuf, h32, bar, ring, ring - 1);
}